// Round 1
// baseline (3180.739 us; speedup 1.0000x reference)
//
#include <hip/hip_runtime.h>

#define NN      13824     // 24^3 neurons
#define BB      256       // batch
#define KDIM    512       // input dim
#define ODIM    1000      // output dim
#define CUBE    24

__device__ __forceinline__ float fast_tanh(float a) {
    // tanh(a) = 1 - 2/(exp(2a)+1); __expf -> v_exp_f32, fine within 2.6e-2 tol
    float e = __expf(2.0f * a);
    return 1.0f - 2.0f / (e + 1.0f);
}

// ---------------------------------------------------------------------------
// x_proj[n][b] = b_in[n] + sum_k x[b][k] * W_in[n][k]
// grid (216, 4), 256 threads. 64n x 64b tile, 4x4 per thread, K-chunks of 16.
// ---------------------------------------------------------------------------
__global__ __launch_bounds__(256) void xproj_kernel(
    const float* __restrict__ x, const float* __restrict__ w,
    const float* __restrict__ bias, float* __restrict__ xp)
{
    __shared__ float Wt[16][68];  // [k][n], padded to 68 (16B-aligned rows, no conflicts)
    __shared__ float Xt[16][68];  // [k][b]
    const int tid = threadIdx.x;
    const int n0 = blockIdx.x * 64, b0 = blockIdx.y * 64;
    const int lr = tid >> 2;          // 0..63 row within tile
    const int lk = (tid & 3) * 4;     // k sub-offset 0,4,8,12
    const int tn = tid & 15, tb = tid >> 4;

    float acc[4][4] = {};

    for (int k0 = 0; k0 < KDIM; k0 += 16) {
        float4 wv = *(const float4*)&w[(size_t)(n0 + lr) * KDIM + k0 + lk];
        float4 xv = *(const float4*)&x[(size_t)(b0 + lr) * KDIM + k0 + lk];
        __syncthreads();
        Wt[lk + 0][lr] = wv.x; Wt[lk + 1][lr] = wv.y;
        Wt[lk + 2][lr] = wv.z; Wt[lk + 3][lr] = wv.w;
        Xt[lk + 0][lr] = xv.x; Xt[lk + 1][lr] = xv.y;
        Xt[lk + 2][lr] = xv.z; Xt[lk + 3][lr] = xv.w;
        __syncthreads();
#pragma unroll
        for (int k = 0; k < 16; ++k) {
            float4 a = *(const float4*)&Wt[k][tn * 4];
            float4 b = *(const float4*)&Xt[k][tb * 4];
            float av[4] = {a.x, a.y, a.z, a.w};
            float bv[4] = {b.x, b.y, b.z, b.w};
#pragma unroll
            for (int i = 0; i < 4; ++i)
#pragma unroll
                for (int j = 0; j < 4; ++j)
                    acc[i][j] += av[i] * bv[j];
        }
    }

#pragma unroll
    for (int i = 0; i < 4; ++i) {
        float bv = bias[n0 + tn * 4 + i];
        float4 st = {acc[i][0] + bv, acc[i][1] + bv, acc[i][2] + bv, acc[i][3] + bv};
        *(float4*)&xp[(size_t)(n0 + tn * 4 + i) * BB + b0 + tb * 4] = st;
    }
}

// ---------------------------------------------------------------------------
// h1 = tanh(x_proj)   (first step: h0 == 0 so stencil contributes nothing)
// ---------------------------------------------------------------------------
__global__ __launch_bounds__(256) void init_kernel(
    const float* __restrict__ xp, float* __restrict__ h)
{
    int i = (blockIdx.x * 256 + threadIdx.x) * 4;
    float4 v = *(const float4*)&xp[i];
    float4 o = {fast_tanh(v.x), fast_tanh(v.y), fast_tanh(v.z), fast_tanh(v.w)};
    *(float4*)&h[i] = o;
}

// ---------------------------------------------------------------------------
// One recurrent step: hnext[n][b] = tanh(xp[n][b] + sum_k W_local[n][k]*hprev[nbr])
// grid 512 blocks x 256 thr. Block = 27 neurons x full 256 batch.
// Wave covers 128 batch as float2; n is wave-uniform (scalar weights/branches).
// ---------------------------------------------------------------------------
__global__ __launch_bounds__(256) void step_kernel(
    const float* __restrict__ hprev, const float* __restrict__ xp,
    const float* __restrict__ wl, float* __restrict__ hnext)
{
    const int tid  = threadIdx.x;
    const int wv_  = tid >> 6;
    const int lane = tid & 63;
    const int n0   = blockIdx.x * 27;
    const int bh   = wv_ & 1;                 // batch half
    const int boff = bh * 128 + lane * 2;
    const int istart = __builtin_amdgcn_readfirstlane(wv_ >> 1);

    for (int i = istart; i < 27; i += 2) {
        const int n = n0 + i;                 // wave-uniform
        const int z = n / 576;
        const int r = n - z * 576;
        const int y = r / 24;
        const int x = r - y * 24;

        float2 acc = *(const float2*)&xp[(size_t)n * BB + boff];

#pragma unroll
        for (int dz = -1; dz <= 1; ++dz) {
            const int zz = z + dz;
            if (zz < 0 || zz >= CUBE) continue;           // scalar branch
#pragma unroll
            for (int dy = -1; dy <= 1; ++dy) {
                const int yy = y + dy;
                if (yy < 0 || yy >= CUBE) continue;       // scalar branch
                const int base = (zz * 24 + yy) * 24;
#pragma unroll
                for (int dx = -1; dx <= 1; ++dx) {
                    const int xx = x + dx;
                    if (xx < 0 || xx >= CUBE) continue;   // scalar branch
                    const float w = wl[n * 27 + (dz + 1) * 9 + (dy + 1) * 3 + (dx + 1)]; // s_load
                    const float2 h2 = *(const float2*)&hprev[(size_t)(base + xx) * BB + boff];
                    acc.x += w * h2.x;
                    acc.y += w * h2.y;
                }
            }
        }
        float2 o = {fast_tanh(acc.x), fast_tanh(acc.y)};
        *(float2*)&hnext[(size_t)n * BB + boff] = o;
    }
}

// ---------------------------------------------------------------------------
// Output GEMM, split-K=4: part[kc][o][b] = sum_{k in chunk} W_out[o][k]*h[k][b]
// grid (16, 4, 4), 256 threads; 64o x 64b tile, 4x4 per thread.
// ---------------------------------------------------------------------------
__global__ __launch_bounds__(256) void outgemm_kernel(
    const float* __restrict__ wout, const float* __restrict__ h,
    float* __restrict__ part)
{
    __shared__ float Wt[16][68];  // [k][o]
    __shared__ float Ht[16][68];  // [k][b]
    const int tid = threadIdx.x;
    const int o0 = blockIdx.x * 64, b0 = blockIdx.y * 64;
    const int kbase = blockIdx.z * (NN / 4);
    const int lr = tid >> 2;
    const int lk = (tid & 3) * 4;
    const int hk = tid >> 4;          // 0..15 (k for H loader)
    const int hb = (tid & 15) * 4;    // b offset for H loader
    const int tn = tid & 15, tb = tid >> 4;
    const bool wvalid = (o0 + lr) < ODIM;

    float acc[4][4] = {};

    for (int k0 = 0; k0 < NN / 4; k0 += 16) {
        float4 wv = {0.f, 0.f, 0.f, 0.f};
        if (wvalid)
            wv = *(const float4*)&wout[(size_t)(o0 + lr) * NN + kbase + k0 + lk];
        float4 hv = *(const float4*)&h[(size_t)(kbase + k0 + hk) * BB + b0 + hb];
        __syncthreads();
        Wt[lk + 0][lr] = wv.x; Wt[lk + 1][lr] = wv.y;
        Wt[lk + 2][lr] = wv.z; Wt[lk + 3][lr] = wv.w;
        *(float4*)&Ht[hk][hb] = hv;
        __syncthreads();
#pragma unroll
        for (int k = 0; k < 16; ++k) {
            float4 a = *(const float4*)&Wt[k][tn * 4];
            float4 b = *(const float4*)&Ht[k][tb * 4];
            float av[4] = {a.x, a.y, a.z, a.w};
            float bv[4] = {b.x, b.y, b.z, b.w};
#pragma unroll
            for (int i = 0; i < 4; ++i)
#pragma unroll
                for (int j = 0; j < 4; ++j)
                    acc[i][j] += av[i] * bv[j];
        }
    }

#pragma unroll
    for (int i = 0; i < 4; ++i) {
        float4 st = {acc[i][0], acc[i][1], acc[i][2], acc[i][3]};
        *(float4*)&part[((size_t)blockIdx.z * 1024 + o0 + tn * 4 + i) * BB + b0 + tb * 4] = st;
    }
}

// out[b*1000+o] = b_out[o] + sum_kc part[kc][o][b]
__global__ __launch_bounds__(256) void reduce_kernel(
    const float* __restrict__ part, const float* __restrict__ bias,
    float* __restrict__ out)
{
    const int i = blockIdx.x * 256 + threadIdx.x;   // 0..255999
    const int b = i / ODIM;
    const int o = i - b * ODIM;
    float s = bias[o];
#pragma unroll
    for (int kc = 0; kc < 4; ++kc)
        s += part[(size_t)kc * 1024 * BB + (size_t)o * BB + b];
    out[i] = s;
}

extern "C" void kernel_launch(void* const* d_in, const int* in_sizes, int n_in,
                              void* d_out, int out_size, void* d_ws, size_t ws_size,
                              hipStream_t stream)
{
    const float* x       = (const float*)d_in[0];
    const float* w_in    = (const float*)d_in[1];
    const float* b_in    = (const float*)d_in[2];
    const float* w_local = (const float*)d_in[3];
    const float* w_out   = (const float*)d_in[4];
    const float* b_out   = (const float*)d_in[5];
    float* out = (float*)d_out;

    float* xp   = (float*)d_ws;            // NN*BB
    float* hA   = xp + (size_t)NN * BB;    // NN*BB
    float* hB   = hA + (size_t)NN * BB;    // NN*BB
    float* part = hB + (size_t)NN * BB;    // 4*1024*BB

    xproj_kernel<<<dim3(216, 4), 256, 0, stream>>>(x, w_in, b_in, xp);
    init_kernel<<<3456, 256, 0, stream>>>(xp, hA);

    const float* hp = hA;
    float* hn = hB;
    for (int s = 0; s < 29; ++s) {
        step_kernel<<<512, 256, 0, stream>>>(hp, xp, w_local, hn);
        float* t = (float*)hp; hp = hn; hn = t;
    }

    outgemm_kernel<<<dim3(16, 4, 4), 256, 0, stream>>>(w_out, hp, part);
    reduce_kernel<<<1000, 256, 0, stream>>>(part, b_out, out);
}

// Round 2
// 931.309 us; speedup vs baseline: 3.4153x; 3.4153x over previous
//
#include <hip/hip_runtime.h>

#define NN      13824     // 24^3 neurons
#define BB      256       // batch
#define KDIM    512       // input dim
#define ODIM    1000      // output dim
#define CUBE    24
#define KSPLIT  12        // out-gemm split-K chunks (part aliases xp: 12.6MB <= 14.2MB)

__device__ __forceinline__ float fast_tanh(float a) {
    float e = __expf(2.0f * a);
    return 1.0f - 2.0f / (e + 1.0f);
}

// ---------------------------------------------------------------------------
// x_proj[n][b] = b_in[n] + sum_k x[b][k] * W_in[n][k]
// ---------------------------------------------------------------------------
__global__ __launch_bounds__(256) void xproj_kernel(
    const float* __restrict__ x, const float* __restrict__ w,
    const float* __restrict__ bias, float* __restrict__ xp)
{
    __shared__ float Wt[16][68];
    __shared__ float Xt[16][68];
    const int tid = threadIdx.x;
    const int n0 = blockIdx.x * 64, b0 = blockIdx.y * 64;
    const int lr = tid >> 2;
    const int lk = (tid & 3) * 4;
    const int tn = tid & 15, tb = tid >> 4;

    float acc[4][4] = {};

    for (int k0 = 0; k0 < KDIM; k0 += 16) {
        float4 wv = *(const float4*)&w[(size_t)(n0 + lr) * KDIM + k0 + lk];
        float4 xv = *(const float4*)&x[(size_t)(b0 + lr) * KDIM + k0 + lk];
        __syncthreads();
        Wt[lk + 0][lr] = wv.x; Wt[lk + 1][lr] = wv.y;
        Wt[lk + 2][lr] = wv.z; Wt[lk + 3][lr] = wv.w;
        Xt[lk + 0][lr] = xv.x; Xt[lk + 1][lr] = xv.y;
        Xt[lk + 2][lr] = xv.z; Xt[lk + 3][lr] = xv.w;
        __syncthreads();
#pragma unroll
        for (int k = 0; k < 16; ++k) {
            float4 a = *(const float4*)&Wt[k][tn * 4];
            float4 b = *(const float4*)&Xt[k][tb * 4];
            float av[4] = {a.x, a.y, a.z, a.w};
            float bv[4] = {b.x, b.y, b.z, b.w};
#pragma unroll
            for (int i = 0; i < 4; ++i)
#pragma unroll
                for (int j = 0; j < 4; ++j)
                    acc[i][j] += av[i] * bv[j];
        }
    }

#pragma unroll
    for (int i = 0; i < 4; ++i) {
        float bv = bias[n0 + tn * 4 + i];
        float4 st = {acc[i][0] + bv, acc[i][1] + bv, acc[i][2] + bv, acc[i][3] + bv};
        *(float4*)&xp[(size_t)(n0 + tn * 4 + i) * BB + b0 + tb * 4] = st;
    }
}

// ---------------------------------------------------------------------------
// h1 = tanh(x_proj)
// ---------------------------------------------------------------------------
__global__ __launch_bounds__(256) void init_kernel(
    const float* __restrict__ xp, float* __restrict__ h)
{
    int i = (blockIdx.x * 256 + threadIdx.x) * 4;
    float4 v = *(const float4*)&xp[i];
    float4 o = {fast_tanh(v.x), fast_tanh(v.y), fast_tanh(v.z), fast_tanh(v.w)};
    *(float4*)&h[i] = o;
}

// ---------------------------------------------------------------------------
// Recurrent step, register sliding window along x.
// Wave = (z,y) column, x-chunk of 6, batch-half of 128 (float2/lane).
// Block = 4 waves (both batch halves x two adjacent x-chunks).
// Grid = 1152 blocks; bid%8 == z/3 for XCD-L2 locality.
// ---------------------------------------------------------------------------
__device__ __forceinline__ void load_plane(
    const float* __restrict__ hprev, int z, int y, int xx, int boff, float2* w9)
{
#pragma unroll
    for (int j = 0; j < 9; ++j) {
        const int dz = j / 3 - 1, dy = j % 3 - 1;
        const int zz = z + dz, yy = y + dy;
        const bool valid = (xx >= 0) & (xx < CUBE) & (zz >= 0) & (zz < CUBE) &
                           (yy >= 0) & (yy < CUBE);   // wave-uniform
        float2 v = {0.f, 0.f};
        if (valid)
            v = *(const float2*)&hprev[(size_t)((zz * 24 + yy) * 24 + xx) * BB + boff];
        w9[j] = v;
    }
}

__global__ __launch_bounds__(256) void step_kernel(
    const float* __restrict__ hprev, const float* __restrict__ xp,
    const float* __restrict__ wl, float* __restrict__ hnext)
{
    const int tid  = threadIdx.x;
    const int wv   = __builtin_amdgcn_readfirstlane(tid >> 6);
    const int lane = tid & 63;

    const int bid   = blockIdx.x;
    const int zhi   = bid & 7;       // z/3  (XCD slab under %8 round-robin)
    const int inner = bid >> 3;      // 0..143
    const int y     = inner % 24;
    const int rest  = inner / 24;    // 0..5
    const int zlo   = rest % 3;
    const int xcp   = rest / 3;      // 0..1
    const int z     = zhi * 3 + zlo;

    const int bh   = wv >> 1;
    const int xc   = xcp * 2 + (wv & 1);   // 0..3
    const int x0   = xc * 6;
    const int boff = bh * 128 + lane * 2;

    float2 win[3][9];
    load_plane(hprev, z, y, x0 - 1, boff, win[0]);
    load_plane(hprev, z, y, x0,     boff, win[1]);

#pragma unroll
    for (int xi = 0; xi < 6; ++xi) {
        const int x = x0 + xi;
        load_plane(hprev, z, y, x + 1, boff, win[(xi + 2) % 3]);

        const int n = (z * 24 + y) * 24 + x;      // wave-uniform
        const float* __restrict__ wn = &wl[(size_t)n * 27];
        float2 acc = *(const float2*)&xp[(size_t)n * BB + boff];

        const float2* pm = win[xi % 3];
        const float2* pc = win[(xi + 1) % 3];
        const float2* pp = win[(xi + 2) % 3];
#pragma unroll
        for (int j = 0; j < 9; ++j) {
            const float w0 = wn[3 * j + 0];
            const float w1 = wn[3 * j + 1];
            const float w2 = wn[3 * j + 2];
            acc.x += w0 * pm[j].x + w1 * pc[j].x + w2 * pp[j].x;
            acc.y += w0 * pm[j].y + w1 * pc[j].y + w2 * pp[j].y;
        }
        float2 o = {fast_tanh(acc.x), fast_tanh(acc.y)};
        *(float2*)&hnext[(size_t)n * BB + boff] = o;
    }
}

// ---------------------------------------------------------------------------
// Output GEMM, split-K=12: part[kc][o][b] = sum_{k chunk} W_out[o][k]*h[k][b]
// grid (16, 4, 12), 256 threads; 64o x 64b tile, 4x4 per thread.
// ---------------------------------------------------------------------------
__global__ __launch_bounds__(256) void outgemm_kernel(
    const float* __restrict__ wout, const float* __restrict__ h,
    float* __restrict__ part)
{
    __shared__ float Wt[16][68];
    __shared__ float Ht[16][68];
    const int tid = threadIdx.x;
    const int o0 = blockIdx.x * 64, b0 = blockIdx.y * 64;
    const int kbase = blockIdx.z * (NN / KSPLIT);
    const int lr = tid >> 2;
    const int lk = (tid & 3) * 4;
    const int hk = tid >> 4;
    const int hb = (tid & 15) * 4;
    const int tn = tid & 15, tb = tid >> 4;
    const bool wvalid = (o0 + lr) < ODIM;

    float acc[4][4] = {};

    for (int k0 = 0; k0 < NN / KSPLIT; k0 += 16) {
        float4 wv = {0.f, 0.f, 0.f, 0.f};
        if (wvalid)
            wv = *(const float4*)&wout[(size_t)(o0 + lr) * NN + kbase + k0 + lk];
        float4 hv = *(const float4*)&h[(size_t)(kbase + k0 + hk) * BB + b0 + hb];
        __syncthreads();
        Wt[lk + 0][lr] = wv.x; Wt[lk + 1][lr] = wv.y;
        Wt[lk + 2][lr] = wv.z; Wt[lk + 3][lr] = wv.w;
        *(float4*)&Ht[hk][hb] = hv;
        __syncthreads();
#pragma unroll
        for (int k = 0; k < 16; ++k) {
            float4 a = *(const float4*)&Wt[k][tn * 4];
            float4 b = *(const float4*)&Ht[k][tb * 4];
            float av[4] = {a.x, a.y, a.z, a.w};
            float bv[4] = {b.x, b.y, b.z, b.w};
#pragma unroll
            for (int i = 0; i < 4; ++i)
#pragma unroll
                for (int j = 0; j < 4; ++j)
                    acc[i][j] += av[i] * bv[j];
        }
    }

#pragma unroll
    for (int i = 0; i < 4; ++i) {
        float4 st = {acc[i][0], acc[i][1], acc[i][2], acc[i][3]};
        *(float4*)&part[((size_t)blockIdx.z * 1024 + o0 + tn * 4 + i) * BB + b0 + tb * 4] = st;
    }
}

__global__ __launch_bounds__(256) void reduce_kernel(
    const float* __restrict__ part, const float* __restrict__ bias,
    float* __restrict__ out)
{
    const int i = blockIdx.x * 256 + threadIdx.x;   // 0..255999
    const int b = i / ODIM;
    const int o = i - b * ODIM;
    float s = bias[o];
#pragma unroll
    for (int kc = 0; kc < KSPLIT; ++kc)
        s += part[(size_t)kc * 1024 * BB + (size_t)o * BB + b];
    out[i] = s;
}

extern "C" void kernel_launch(void* const* d_in, const int* in_sizes, int n_in,
                              void* d_out, int out_size, void* d_ws, size_t ws_size,
                              hipStream_t stream)
{
    const float* x       = (const float*)d_in[0];
    const float* w_in    = (const float*)d_in[1];
    const float* b_in    = (const float*)d_in[2];
    const float* w_local = (const float*)d_in[3];
    const float* w_out   = (const float*)d_in[4];
    const float* b_out   = (const float*)d_in[5];
    float* out = (float*)d_out;

    float* xp   = (float*)d_ws;            // NN*BB floats
    float* hA   = xp + (size_t)NN * BB;
    float* hB   = hA + (size_t)NN * BB;
    float* part = xp;                      // aliases xp (dead after last step)

    xproj_kernel<<<dim3(216, 4), 256, 0, stream>>>(x, w_in, b_in, xp);
    init_kernel<<<3456, 256, 0, stream>>>(xp, hA);

    const float* hp = hA;
    float* hn = hB;
    for (int s = 0; s < 29; ++s) {
        step_kernel<<<1152, 256, 0, stream>>>(hp, xp, w_local, hn);
        float* t = (float*)hp; hp = hn; hn = t;
    }

    outgemm_kernel<<<dim3(16, 4, KSPLIT), 256, 0, stream>>>(w_out, hp, part);
    reduce_kernel<<<1000, 256, 0, stream>>>(part, b_out, out);
}

// Round 3
// 710.620 us; speedup vs baseline: 4.4760x; 1.3106x over previous
//
#include <hip/hip_runtime.h>

#define NN      13824     // 24^3 neurons
#define BB      256       // batch
#define KDIM    512       // input dim
#define ODIM    1000      // output dim
#define CUBE    24
#define KSPLIT  24        // out-gemm split-K chunks; part (25.2MB) aliases xp+hA (28.3MB)

__device__ __forceinline__ float fast_tanh(float a) {
    float e = __expf(2.0f * a);
    return 1.0f - 2.0f / (e + 1.0f);
}

// ---------------------------------------------------------------------------
// x_proj[n][b] = b_in[n] + sum_k x[b][k] * W_in[n][k]
// ---------------------------------------------------------------------------
__global__ __launch_bounds__(256) void xproj_kernel(
    const float* __restrict__ x, const float* __restrict__ w,
    const float* __restrict__ bias, float* __restrict__ xp)
{
    __shared__ float Wt[16][68];
    __shared__ float Xt[16][68];
    const int tid = threadIdx.x;
    const int n0 = blockIdx.x * 64, b0 = blockIdx.y * 64;
    const int lr = tid >> 2;
    const int lk = (tid & 3) * 4;
    const int tn = tid & 15, tb = tid >> 4;

    float acc[4][4] = {};

    for (int k0 = 0; k0 < KDIM; k0 += 16) {
        float4 wv = *(const float4*)&w[(size_t)(n0 + lr) * KDIM + k0 + lk];
        float4 xv = *(const float4*)&x[(size_t)(b0 + lr) * KDIM + k0 + lk];
        __syncthreads();
        Wt[lk + 0][lr] = wv.x; Wt[lk + 1][lr] = wv.y;
        Wt[lk + 2][lr] = wv.z; Wt[lk + 3][lr] = wv.w;
        Xt[lk + 0][lr] = xv.x; Xt[lk + 1][lr] = xv.y;
        Xt[lk + 2][lr] = xv.z; Xt[lk + 3][lr] = xv.w;
        __syncthreads();
#pragma unroll
        for (int k = 0; k < 16; ++k) {
            float4 a = *(const float4*)&Wt[k][tn * 4];
            float4 b = *(const float4*)&Xt[k][tb * 4];
            float av[4] = {a.x, a.y, a.z, a.w};
            float bv[4] = {b.x, b.y, b.z, b.w};
#pragma unroll
            for (int i = 0; i < 4; ++i)
#pragma unroll
                for (int j = 0; j < 4; ++j)
                    acc[i][j] += av[i] * bv[j];
        }
    }

#pragma unroll
    for (int i = 0; i < 4; ++i) {
        float bv = bias[n0 + tn * 4 + i];
        float4 st = {acc[i][0] + bv, acc[i][1] + bv, acc[i][2] + bv, acc[i][3] + bv};
        *(float4*)&xp[(size_t)(n0 + tn * 4 + i) * BB + b0 + tb * 4] = st;
    }
}

// ---------------------------------------------------------------------------
// h1 = tanh(x_proj)
// ---------------------------------------------------------------------------
__global__ __launch_bounds__(256) void init_kernel(
    const float* __restrict__ xp, float* __restrict__ h)
{
    int i = (blockIdx.x * 256 + threadIdx.x) * 4;
    float4 v = *(const float4*)&xp[i];
    float4 o = {fast_tanh(v.x), fast_tanh(v.y), fast_tanh(v.z), fast_tanh(v.w)};
    *(float4*)&h[i] = o;
}

// ---------------------------------------------------------------------------
// Recurrent step v3: register sliding window along x, prefetch distance 2.
// Wave = one (z,y) line, x-chunk of 6, 64-batch quarter (1 float/lane).
// Block = 4 waves = the 4 batch quarters of one (z,y,xc) -> coalesced halo.
// Grid = 2304 blocks; bid%8 == z/3 for XCD-L2 locality.
// ---------------------------------------------------------------------------
__device__ __forceinline__ void load_plane1(
    const float* __restrict__ hprev, int z, int y, int xx, int boff, float* w9)
{
#pragma unroll
    for (int j = 0; j < 9; ++j) {
        const int dz = j / 3 - 1, dy = j % 3 - 1;
        const int zz = z + dz, yy = y + dy;
        const bool valid = (xx >= 0) & (xx < CUBE) & (zz >= 0) & (zz < CUBE) &
                           (yy >= 0) & (yy < CUBE);   // wave-uniform
        float v = 0.f;
        if (valid)
            v = hprev[(size_t)((zz * 24 + yy) * 24 + xx) * BB + boff];
        w9[j] = v;
    }
}

__global__ __launch_bounds__(256) void step_kernel(
    const float* __restrict__ hprev, const float* __restrict__ xp,
    const float* __restrict__ wl, float* __restrict__ hnext)
{
    const int tid  = threadIdx.x;
    const int wv   = __builtin_amdgcn_readfirstlane(tid >> 6);  // batch quarter, uniform
    const int lane = tid & 63;

    const int bid   = blockIdx.x;
    const int zhi   = bid & 7;        // z/3 (XCD slab under %8 round-robin)
    const int inner = bid >> 3;       // 0..287
    const int y     = inner % 24;
    const int r     = inner / 24;     // 0..11
    const int xc    = r & 3;          // x-chunk 0..3
    const int zlo   = r >> 2;         // 0..2
    const int z     = zhi * 3 + zlo;

    const int x0   = xc * 6;
    const int boff = wv * 64 + lane;

    // ring-5 window of (dz,dy) planes; slot s holds plane x = (x0-1) + ((s - 0 + 5*k))
    float win[5][9];
    load_plane1(hprev, z, y, x0 - 1, boff, win[0]);
    load_plane1(hprev, z, y, x0,     boff, win[1]);
    load_plane1(hprev, z, y, x0 + 1, boff, win[2]);
    load_plane1(hprev, z, y, x0 + 2, boff, win[3]);

#pragma unroll
    for (int xi = 0; xi < 6; ++xi) {
        const int x = x0 + xi;
        // prefetch plane x+3 (consumed 2 iterations from now); planes beyond
        // x0+6 are never used -> skip dead prefetches
        if (xi <= 3)
            load_plane1(hprev, z, y, x + 3, boff, win[(xi + 4) % 5]);

        const int n = (z * 24 + y) * 24 + x;            // wave-uniform
        const float* __restrict__ wn = &wl[(size_t)n * 27];
        float acc = xp[(size_t)n * BB + boff];

        const float* pm = win[xi % 5];         // plane x-1
        const float* pc = win[(xi + 1) % 5];   // plane x
        const float* pp = win[(xi + 2) % 5];   // plane x+1
#pragma unroll
        for (int j = 0; j < 9; ++j) {
            acc += wn[3 * j + 0] * pm[j];
            acc += wn[3 * j + 1] * pc[j];
            acc += wn[3 * j + 2] * pp[j];
        }
        hnext[(size_t)n * BB + boff] = fast_tanh(acc);
    }
}

// ---------------------------------------------------------------------------
// Output GEMM, split-K=24: part[kc][o][b] = sum_{k chunk} W_out[o][k]*h[k][b]
// grid (16, 4, 24), 256 threads; 64o x 64b tile, 4x4 per thread.
// ---------------------------------------------------------------------------
__global__ __launch_bounds__(256) void outgemm_kernel(
    const float* __restrict__ wout, const float* __restrict__ h,
    float* __restrict__ part)
{
    __shared__ float Wt[16][68];
    __shared__ float Ht[16][68];
    const int tid = threadIdx.x;
    const int o0 = blockIdx.x * 64, b0 = blockIdx.y * 64;
    const int kbase = blockIdx.z * (NN / KSPLIT);
    const int lr = tid >> 2;
    const int lk = (tid & 3) * 4;
    const int hk = tid >> 4;
    const int hb = (tid & 15) * 4;
    const int tn = tid & 15, tb = tid >> 4;
    const bool wvalid = (o0 + lr) < ODIM;

    float acc[4][4] = {};

    for (int k0 = 0; k0 < NN / KSPLIT; k0 += 16) {
        float4 wv = {0.f, 0.f, 0.f, 0.f};
        if (wvalid)
            wv = *(const float4*)&wout[(size_t)(o0 + lr) * NN + kbase + k0 + lk];
        float4 hv = *(const float4*)&h[(size_t)(kbase + k0 + hk) * BB + b0 + hb];
        __syncthreads();
        Wt[lk + 0][lr] = wv.x; Wt[lk + 1][lr] = wv.y;
        Wt[lk + 2][lr] = wv.z; Wt[lk + 3][lr] = wv.w;
        *(float4*)&Ht[hk][hb] = hv;
        __syncthreads();
#pragma unroll
        for (int k = 0; k < 16; ++k) {
            float4 a = *(const float4*)&Wt[k][tn * 4];
            float4 b = *(const float4*)&Ht[k][tb * 4];
            float av[4] = {a.x, a.y, a.z, a.w};
            float bv[4] = {b.x, b.y, b.z, b.w};
#pragma unroll
            for (int i = 0; i < 4; ++i)
#pragma unroll
                for (int j = 0; j < 4; ++j)
                    acc[i][j] += av[i] * bv[j];
        }
    }

#pragma unroll
    for (int i = 0; i < 4; ++i) {
        float4 st = {acc[i][0], acc[i][1], acc[i][2], acc[i][3]};
        *(float4*)&part[((size_t)blockIdx.z * 1024 + o0 + tn * 4 + i) * BB + b0 + tb * 4] = st;
    }
}

__global__ __launch_bounds__(256) void reduce_kernel(
    const float* __restrict__ part, const float* __restrict__ bias,
    float* __restrict__ out)
{
    const int i = blockIdx.x * 256 + threadIdx.x;   // 0..255999
    const int b = i / ODIM;
    const int o = i - b * ODIM;
    float s = bias[o];
#pragma unroll
    for (int kc = 0; kc < KSPLIT; ++kc)
        s += part[(size_t)kc * 1024 * BB + (size_t)o * BB + b];
    out[i] = s;
}

extern "C" void kernel_launch(void* const* d_in, const int* in_sizes, int n_in,
                              void* d_out, int out_size, void* d_ws, size_t ws_size,
                              hipStream_t stream)
{
    const float* x       = (const float*)d_in[0];
    const float* w_in    = (const float*)d_in[1];
    const float* b_in    = (const float*)d_in[2];
    const float* w_local = (const float*)d_in[3];
    const float* w_out   = (const float*)d_in[4];
    const float* b_out   = (const float*)d_in[5];
    float* out = (float*)d_out;

    float* xp   = (float*)d_ws;            // NN*BB floats
    float* hA   = xp + (size_t)NN * BB;
    float* hB   = hA + (size_t)NN * BB;
    float* part = xp;                      // aliases xp+hA (both dead after last step)

    xproj_kernel<<<dim3(216, 4), 256, 0, stream>>>(x, w_in, b_in, xp);
    init_kernel<<<3456, 256, 0, stream>>>(xp, hA);

    const float* hp = hA;
    float* hn = hB;
    for (int s = 0; s < 29; ++s) {          // 29 odd -> final hp == hB (part alias safe)
        step_kernel<<<2304, 256, 0, stream>>>(hp, xp, w_local, hn);
        float* t = (float*)hp; hp = hn; hn = t;
    }

    outgemm_kernel<<<dim3(16, 4, KSPLIT), 256, 0, stream>>>(w_out, hp, part);
    reduce_kernel<<<1000, 256, 0, stream>>>(part, b_out, out);
}

// Round 4
// 598.400 us; speedup vs baseline: 5.3154x; 1.1875x over previous
//
#include <hip/hip_runtime.h>

#define NN   13824     // 24^3 neurons
#define BB   256       // batch
#define KDIM 512       // input dim
#define ODIM 1000      // output dim
#define CUBE 24
#define KS   16        // out-gemm split-K

typedef short bf8 __attribute__((ext_vector_type(8)));     // 8 bf16 (4 VGPRs)
typedef float f32x4 __attribute__((ext_vector_type(4)));   // MFMA acc

__device__ __forceinline__ float fast_tanh(float a) {
    float e = __expf(2.0f * a);
    return 1.0f - 2.0f / (e + 1.0f);
}
__device__ __forceinline__ float bf_lo(unsigned u) { return __uint_as_float(u << 16); }
__device__ __forceinline__ float bf_hi(unsigned u) { return __uint_as_float(u & 0xffff0000u); }
__device__ __forceinline__ unsigned short bf_rne(float f) {
    unsigned u = __float_as_uint(f);
    u += 0x7fffu + ((u >> 16) & 1u);
    return (unsigned short)(u >> 16);
}
__device__ __forceinline__ unsigned bf_pack(float lo, float hi) {
    return (unsigned)bf_rne(lo) | ((unsigned)bf_rne(hi) << 16);
}
__device__ __forceinline__ bf8 cvt8(float4 a, float4 b) {
    bf8 r;
    r[0] = (short)bf_rne(a.x); r[1] = (short)bf_rne(a.y);
    r[2] = (short)bf_rne(a.z); r[3] = (short)bf_rne(a.w);
    r[4] = (short)bf_rne(b.x); r[5] = (short)bf_rne(b.y);
    r[6] = (short)bf_rne(b.z); r[7] = (short)bf_rne(b.w);
    return r;
}

// ---------------------------------------------------------------------------
// x (fp32 [256][512]) -> x_bf (bf16, packed dwords). 65536 dwords.
// ---------------------------------------------------------------------------
__global__ __launch_bounds__(256) void xbf_kernel(
    const float* __restrict__ x, unsigned* __restrict__ xb)
{
    int i = blockIdx.x * 256 + threadIdx.x;
    float2 v = *(const float2*)&x[(size_t)i * 2];
    xb[i] = bf_pack(v.x, v.y);
}

// ---------------------------------------------------------------------------
// xproj via MFMA: xp[n][b] = bias[n] + sum_k W_in[n][k]*x[b][k]  (bf16 out)
// grid 864 (n-tiles of 16), 4 waves; wave w covers b-range w*64 (4 16x16 tiles).
// A = W_in rows (cvt fp32->bf16 in-kernel, L1-shared across waves), B = x_bf.
// ---------------------------------------------------------------------------
__global__ __launch_bounds__(256) void xproj_mfma(
    const float* __restrict__ w_in, const float* __restrict__ bias,
    const short* __restrict__ xbf, unsigned short* __restrict__ xp)
{
    const int tid = threadIdx.x, w = tid >> 6, lane = tid & 63;
    const int quad = lane >> 4, l16 = lane & 15;
    const int n0 = blockIdx.x * 16;
    const float* __restrict__ arow = &w_in[(size_t)(n0 + l16) * KDIM];

    f32x4 acc[4] = {};
    for (int k0 = 0; k0 < KDIM; k0 += 32) {
        const int ka = k0 + quad * 8;
        float4 a0 = *(const float4*)&arow[ka];
        float4 a1 = *(const float4*)&arow[ka + 4];
        bf8 af = cvt8(a0, a1);
#pragma unroll
        for (int j = 0; j < 4; ++j) {
            const int b = w * 64 + j * 16 + l16;
            bf8 bfr = *(const bf8*)&xbf[(size_t)b * KDIM + ka];
            acc[j] = __builtin_amdgcn_mfma_f32_16x16x32_bf16(af, bfr, acc[j], 0, 0, 0);
        }
    }
#pragma unroll
    for (int j = 0; j < 4; ++j) {
        const int b = w * 64 + j * 16 + l16;
#pragma unroll
        for (int r = 0; r < 4; ++r) {
            const int n = n0 + quad * 4 + r;    // C/D: row=quad*4+reg, col=l16
            xp[(size_t)n * BB + b] = bf_rne(acc[j][r] + bias[n]);
        }
    }
}

// ---------------------------------------------------------------------------
// h1 = tanh(xp)   (h0 == 0). Packed-bf16 dwords, 4/thread.
// ---------------------------------------------------------------------------
__global__ __launch_bounds__(256) void init_kernel(
    const unsigned* __restrict__ xp, unsigned* __restrict__ h)
{
    int i = (blockIdx.x * 256 + threadIdx.x) * 4;
    uint4 v = *(const uint4*)&xp[i];
    uint4 o;
    o.x = bf_pack(fast_tanh(bf_lo(v.x)), fast_tanh(bf_hi(v.x)));
    o.y = bf_pack(fast_tanh(bf_lo(v.y)), fast_tanh(bf_hi(v.y)));
    o.z = bf_pack(fast_tanh(bf_lo(v.z)), fast_tanh(bf_hi(v.z)));
    o.w = bf_pack(fast_tanh(bf_lo(v.w)), fast_tanh(bf_hi(v.w)));
    *(uint4*)&h[i] = o;
}

// ---------------------------------------------------------------------------
// Recurrent step, bf16 packed (2 batch/lane), ring-5 window, prefetch dist 2.
// Wave = (z,y) line, x-chunk 6, batch-half 128 (64 dwords). Block = 4 waves.
// Grid 1152; bid&7 == z/3 for XCD-L2 slab locality.
// ---------------------------------------------------------------------------
__device__ __forceinline__ void load_plane_u(
    const unsigned* __restrict__ h32, int z, int y, int xx, int dof, unsigned* w9)
{
#pragma unroll
    for (int j = 0; j < 9; ++j) {
        const int dz = j / 3 - 1, dy = j % 3 - 1;
        const int zz = z + dz, yy = y + dy;
        const bool valid = (xx >= 0) & (xx < CUBE) & (zz >= 0) & (zz < CUBE) &
                           (yy >= 0) & (yy < CUBE);   // wave-uniform
        unsigned v = 0u;
        if (valid) v = h32[(size_t)((zz * 24 + yy) * 24 + xx) * 128 + dof];
        w9[j] = v;
    }
}

__global__ __launch_bounds__(256) void step_kernel(
    const unsigned* __restrict__ hprev, const unsigned* __restrict__ xp,
    const float* __restrict__ wl, unsigned* __restrict__ hnext)
{
    const int tid  = threadIdx.x;
    const int wv   = __builtin_amdgcn_readfirstlane(tid >> 6);
    const int lane = tid & 63;

    const int bid   = blockIdx.x;
    const int zhi   = bid & 7;
    const int inner = bid >> 3;       // 0..143
    const int y     = inner % 24;
    const int r     = inner / 24;     // 0..5
    const int zlo   = r % 3;
    const int xcp   = r / 3;          // 0..1
    const int z     = zhi * 3 + zlo;

    const int xc   = xcp * 2 + (wv & 1);    // 0..3
    const int x0   = xc * 6;
    const int dof  = (wv >> 1) * 64 + lane; // dword offset (2 batch elems)

    unsigned win[5][9];
    load_plane_u(hprev, z, y, x0 - 1, dof, win[0]);
    load_plane_u(hprev, z, y, x0,     dof, win[1]);
    load_plane_u(hprev, z, y, x0 + 1, dof, win[2]);
    load_plane_u(hprev, z, y, x0 + 2, dof, win[3]);

#pragma unroll
    for (int xi = 0; xi < 6; ++xi) {
        const int x = x0 + xi;
        if (xi <= 3)
            load_plane_u(hprev, z, y, x + 3, dof, win[(xi + 4) % 5]);

        const int n = (z * 24 + y) * 24 + x;          // wave-uniform
        const float* __restrict__ wn = &wl[(size_t)n * 27];
        const unsigned xpv = xp[(size_t)n * 128 + dof];
        float acc0 = bf_lo(xpv), acc1 = bf_hi(xpv);

        const unsigned* pm = win[xi % 5];
        const unsigned* pc = win[(xi + 1) % 5];
        const unsigned* pp = win[(xi + 2) % 5];
#pragma unroll
        for (int j = 0; j < 9; ++j) {
            const float w0 = wn[3 * j + 0];
            const float w1 = wn[3 * j + 1];
            const float w2 = wn[3 * j + 2];
            acc0 += w0 * bf_lo(pm[j]) + w1 * bf_lo(pc[j]) + w2 * bf_lo(pp[j]);
            acc1 += w0 * bf_hi(pm[j]) + w1 * bf_hi(pc[j]) + w2 * bf_hi(pp[j]);
        }
        hnext[(size_t)n * 128 + dof] = bf_pack(fast_tanh(acc0), fast_tanh(acc1));
    }
}

// ---------------------------------------------------------------------------
// Transpose h[k][b] -> hT[b][k] (bf16), 64x64 tiles via LDS.
// ---------------------------------------------------------------------------
__global__ __launch_bounds__(256) void transpose_kernel(
    const unsigned* __restrict__ h32, unsigned* __restrict__ hT32)
{
    __shared__ unsigned short T[64][66];
    const int tid = threadIdx.x;
    const int rr = tid >> 2, g = tid & 3;
    const int k0 = blockIdx.x * 64, b0 = blockIdx.y * 64;
#pragma unroll
    for (int i = 0; i < 8; ++i) {
        unsigned d = h32[(size_t)(k0 + rr) * 128 + b0 / 2 + g * 8 + i];
        const int bl = (g * 8 + i) * 2;
        T[bl][rr]     = (unsigned short)(d & 0xffffu);
        T[bl + 1][rr] = (unsigned short)(d >> 16);
    }
    __syncthreads();
#pragma unroll
    for (int i = 0; i < 8; ++i) {
        const int kl = (g * 8 + i) * 2;
        unsigned d = (unsigned)T[rr][kl] | ((unsigned)T[rr][kl + 1] << 16);
        hT32[(size_t)(b0 + rr) * (NN / 2) + k0 / 2 + g * 8 + i] = d;
    }
}

// ---------------------------------------------------------------------------
// Output GEMM via MFMA, split-K=16: part[kc][o][b] = sum W_out[o][k]*hT[b][k]
// grid (32, 16): 32 o-blocks of 32 rows, 16 k-chunks of 864. Block = 4 waves:
// wave covers 16o x 128b (8 tiles). W_out cvt fp32->bf16 in-kernel.
// ---------------------------------------------------------------------------
__global__ __launch_bounds__(256) void outgemm_mfma(
    const float* __restrict__ wout, const short* __restrict__ hT,
    float* __restrict__ part)
{
    const int tid = threadIdx.x, w = tid >> 6, lane = tid & 63;
    const int quad = lane >> 4, l16 = lane & 15;
    const int o0 = blockIdx.x * 32 + (w & 1) * 16;
    const int bh = w >> 1;
    const int kb = blockIdx.y * (NN / KS);
    const int o_row = o0 + l16;
    const bool aval = o_row < ODIM;
    const float* __restrict__ arow = &wout[(size_t)o_row * NN];

    f32x4 acc[8] = {};
    for (int ki = 0; ki < NN / KS; ki += 32) {
        const int ka = kb + ki + quad * 8;
        bf8 af = {};
        if (aval) {
            float4 a0 = *(const float4*)&arow[ka];
            float4 a1 = *(const float4*)&arow[ka + 4];
            af = cvt8(a0, a1);
        }
#pragma unroll
        for (int j = 0; j < 8; ++j) {
            const int b = bh * 128 + j * 16 + l16;
            bf8 bfr = *(const bf8*)&hT[(size_t)b * NN + ka];
            acc[j] = __builtin_amdgcn_mfma_f32_16x16x32_bf16(af, bfr, acc[j], 0, 0, 0);
        }
    }
#pragma unroll
    for (int j = 0; j < 8; ++j) {
        const int b = bh * 128 + j * 16 + l16;
#pragma unroll
        for (int r = 0; r < 4; ++r) {
            const int o = o0 + quad * 4 + r;
            part[((size_t)blockIdx.y * 1024 + o) * BB + b] = acc[j][r];
        }
    }
}

// out[b*1000+o] = bias[o] + sum_kc part[kc][o][b]; block per o, lanes = b.
__global__ __launch_bounds__(256) void reduce_kernel(
    const float* __restrict__ part, const float* __restrict__ bias,
    float* __restrict__ out)
{
    const int o = blockIdx.x, b = threadIdx.x;
    float s = bias[o];
#pragma unroll
    for (int kc = 0; kc < KS; ++kc)
        s += part[((size_t)kc * 1024 + o) * BB + b];
    out[(size_t)b * ODIM + o] = s;
}

extern "C" void kernel_launch(void* const* d_in, const int* in_sizes, int n_in,
                              void* d_out, int out_size, void* d_ws, size_t ws_size,
                              hipStream_t stream)
{
    const float* x       = (const float*)d_in[0];
    const float* w_in    = (const float*)d_in[1];
    const float* b_in    = (const float*)d_in[2];
    const float* w_local = (const float*)d_in[3];
    const float* w_out   = (const float*)d_in[4];
    const float* b_out   = (const float*)d_in[5];
    float* out = (float*)d_out;

    char* p = (char*)d_ws;
    unsigned short* xp_bf = (unsigned short*)p;          p += (size_t)NN * BB * 2;
    unsigned short* hA    = (unsigned short*)p;          p += (size_t)NN * BB * 2;
    unsigned short* hB    = (unsigned short*)p;          p += (size_t)NN * BB * 2;
    unsigned short* hT    = (unsigned short*)p;          p += (size_t)NN * BB * 2;
    unsigned short* x_bf  = (unsigned short*)p;          p += (size_t)BB * KDIM * 2;
    float*          part  = (float*)p;                   // KS*1024*BB floats

    xbf_kernel<<<256, 256, 0, stream>>>(x, (unsigned*)x_bf);
    xproj_mfma<<<864, 256, 0, stream>>>(w_in, b_in, (const short*)x_bf, xp_bf);
    init_kernel<<<1728, 256, 0, stream>>>((const unsigned*)xp_bf, (unsigned*)hA);

    const unsigned* hp = (const unsigned*)hA;
    unsigned* hn = (unsigned*)hB;
    for (int s = 0; s < 29; ++s) {          // 29 odd -> final state in hB
        step_kernel<<<1152, 256, 0, stream>>>(hp, (const unsigned*)xp_bf, w_local, hn);
        unsigned* t = (unsigned*)hp; hp = hn; hn = t;
    }

    transpose_kernel<<<dim3(216, 4), 256, 0, stream>>>(hp, (unsigned*)hT);
    outgemm_mfma<<<dim3(32, KS), 256, 0, stream>>>(w_out, (const short*)hT, part);
    reduce_kernel<<<ODIM, 256, 0, stream>>>(part, b_out, out);
}

// Round 5
// 573.441 us; speedup vs baseline: 5.5468x; 1.0435x over previous
//
#include <hip/hip_runtime.h>
#include <hip/hip_bf16.h>

#define NN   13824     // 24^3 neurons
#define BB   256       // batch
#define KDIM 512       // input dim
#define ODIM 1000      // output dim
#define CUBE 24
#define KS   16        // out-gemm split-K

typedef short bf8 __attribute__((ext_vector_type(8)));     // 8 bf16 (4 VGPRs)
typedef float f32x4 __attribute__((ext_vector_type(4)));   // MFMA acc

__device__ __forceinline__ float fast_tanh(float a) {
    float e = __expf(2.0f * a);
    return 1.0f - 2.0f / (e + 1.0f);
}
__device__ __forceinline__ float bf_lo(unsigned u) { return __uint_as_float(u << 16); }
__device__ __forceinline__ float bf_hi(unsigned u) { return __uint_as_float(u & 0xffff0000u); }
__device__ __forceinline__ unsigned short bf_rne(float f) {
    unsigned u = __float_as_uint(f);
    u += 0x7fffu + ((u >> 16) & 1u);
    return (unsigned short)(u >> 16);
}
// packed fp32x2 -> bf16x2 via v_cvt_pk_bf16_f32 (one inst on gfx950)
__device__ __forceinline__ unsigned pk_bf16(float lo, float hi) {
    union { __hip_bfloat162 h; unsigned u; } cv;
    cv.h = __float22bfloat162_rn(make_float2(lo, hi));
    return cv.u;
}
__device__ __forceinline__ bf8 cvt8(float4 a, float4 b) {
    union { bf8 v; unsigned u[4]; } r;
    r.u[0] = pk_bf16(a.x, a.y);
    r.u[1] = pk_bf16(a.z, a.w);
    r.u[2] = pk_bf16(b.x, b.y);
    r.u[3] = pk_bf16(b.z, b.w);
    return r.v;
}

// ---------------------------------------------------------------------------
// x (fp32 [256][512]) -> x_bf (bf16 packed dwords)
// ---------------------------------------------------------------------------
__global__ __launch_bounds__(256) void xbf_kernel(
    const float* __restrict__ x, unsigned* __restrict__ xb)
{
    int i = blockIdx.x * 256 + threadIdx.x;
    float2 v = *(const float2*)&x[(size_t)i * 2];
    xb[i] = pk_bf16(v.x, v.y);
}

// ---------------------------------------------------------------------------
// xproj via MFMA, software-pipelined, fused h1 = tanh(xp) epilogue.
// grid 864 (16-n tiles), 4 waves; wave w covers b = w*64..w*64+63 (4 tiles).
// ---------------------------------------------------------------------------
__global__ __launch_bounds__(256) void xproj_mfma(
    const float* __restrict__ w_in, const float* __restrict__ bias,
    const short* __restrict__ xbf, unsigned short* __restrict__ xp,
    unsigned short* __restrict__ h1)
{
    const int tid = threadIdx.x, w = tid >> 6, lane = tid & 63;
    const int quad = lane >> 4, l16 = lane & 15;
    const int n0 = blockIdx.x * 16;
    const float* __restrict__ arow = &w_in[(size_t)(n0 + l16) * KDIM];

    f32x4 acc[4] = {};

    int ka = quad * 8;
    float4 a0 = *(const float4*)&arow[ka];
    float4 a1 = *(const float4*)&arow[ka + 4];
    bf8 bb[4];
#pragma unroll
    for (int j = 0; j < 4; ++j)
        bb[j] = *(const bf8*)&xbf[(size_t)(w * 64 + j * 16 + l16) * KDIM + ka];

    for (int it = 0; it < 16; ++it) {
        float4 na0{}, na1{}; bf8 nb[4] = {};
        if (it < 15) {
            const int nka = ka + 32;
            na0 = *(const float4*)&arow[nka];
            na1 = *(const float4*)&arow[nka + 4];
#pragma unroll
            for (int j = 0; j < 4; ++j)
                nb[j] = *(const bf8*)&xbf[(size_t)(w * 64 + j * 16 + l16) * KDIM + nka];
        }
        bf8 af = cvt8(a0, a1);
#pragma unroll
        for (int j = 0; j < 4; ++j)
            acc[j] = __builtin_amdgcn_mfma_f32_16x16x32_bf16(af, bb[j], acc[j], 0, 0, 0);
        a0 = na0; a1 = na1;
#pragma unroll
        for (int j = 0; j < 4; ++j) bb[j] = nb[j];
        ka += 32;
    }

#pragma unroll
    for (int j = 0; j < 4; ++j) {
        const int b = w * 64 + j * 16 + l16;
#pragma unroll
        for (int r = 0; r < 4; ++r) {
            const int n = n0 + quad * 4 + r;
            const float v = acc[j][r] + bias[n];
            xp[(size_t)n * BB + b] = bf_rne(v);
            h1[(size_t)n * BB + b] = bf_rne(fast_tanh(v));
        }
    }
}

// ---------------------------------------------------------------------------
// Recurrent step v4: float2 register window (unpack once at load),
// ring-5, prefetch distance 2. Wave = (z,y) line, x-chunk 6, 128-batch half.
// Block = 2 waves (both halves); grid 2304; bid&7 == z/3 (XCD slab).
// ---------------------------------------------------------------------------
__device__ __forceinline__ void load_plane_f2(
    const unsigned* __restrict__ h32, int z, int y, int xx, int dof, float2* w9)
{
#pragma unroll
    for (int j = 0; j < 9; ++j) {
        const int dz = j / 3 - 1, dy = j % 3 - 1;
        const int zz = z + dz, yy = y + dy;
        const bool valid = (xx >= 0) & (xx < CUBE) & (zz >= 0) & (zz < CUBE) &
                           (yy >= 0) & (yy < CUBE);   // wave-uniform
        unsigned v = 0u;
        if (valid) v = h32[(size_t)((zz * 24 + yy) * 24 + xx) * 128 + dof];
        w9[j] = make_float2(bf_lo(v), bf_hi(v));
    }
}

__global__ __launch_bounds__(128) void step_kernel(
    const unsigned* __restrict__ hprev, const unsigned* __restrict__ xp,
    const float* __restrict__ wl, unsigned* __restrict__ hnext)
{
    const int tid  = threadIdx.x;
    const int wv   = __builtin_amdgcn_readfirstlane(tid >> 6);  // batch half
    const int lane = tid & 63;

    const int bid   = blockIdx.x;
    const int zhi   = bid & 7;
    const int inner = bid >> 3;       // 0..287
    const int y     = inner % 24;
    const int r     = inner / 24;     // 0..11
    const int xc    = r & 3;
    const int zlo   = r >> 2;
    const int z     = zhi * 3 + zlo;

    const int x0   = xc * 6;
    const int dof  = wv * 64 + lane;  // dword offset (2 batch elems)

    float2 win[5][9];
    load_plane_f2(hprev, z, y, x0 - 1, dof, win[0]);
    load_plane_f2(hprev, z, y, x0,     dof, win[1]);
    load_plane_f2(hprev, z, y, x0 + 1, dof, win[2]);
    load_plane_f2(hprev, z, y, x0 + 2, dof, win[3]);

#pragma unroll
    for (int xi = 0; xi < 6; ++xi) {
        const int x = x0 + xi;
        if (xi <= 3)
            load_plane_f2(hprev, z, y, x + 3, dof, win[(xi + 4) % 5]);

        const int n = (z * 24 + y) * 24 + x;          // wave-uniform
        const float* __restrict__ wn = &wl[(size_t)n * 27];
        const unsigned xpv = xp[(size_t)n * 128 + dof];
        float2 acc = make_float2(bf_lo(xpv), bf_hi(xpv));

        const float2* pm = win[xi % 5];
        const float2* pc = win[(xi + 1) % 5];
        const float2* pp = win[(xi + 2) % 5];
#pragma unroll
        for (int j = 0; j < 9; ++j) {
            const float w0 = wn[3 * j + 0];
            const float w1 = wn[3 * j + 1];
            const float w2 = wn[3 * j + 2];
            acc.x += w0 * pm[j].x + w1 * pc[j].x + w2 * pp[j].x;
            acc.y += w0 * pm[j].y + w1 * pc[j].y + w2 * pp[j].y;
        }
        hnext[(size_t)n * 128 + dof] = pk_bf16(fast_tanh(acc.x), fast_tanh(acc.y));
    }
}

// ---------------------------------------------------------------------------
// Transpose h[k][b] -> hT[b][k] (bf16), 64x64 tiles via LDS.
// ---------------------------------------------------------------------------
__global__ __launch_bounds__(256) void transpose_kernel(
    const unsigned* __restrict__ h32, unsigned* __restrict__ hT32)
{
    __shared__ unsigned short T[64][66];
    const int tid = threadIdx.x;
    const int rr = tid >> 2, g = tid & 3;
    const int k0 = blockIdx.x * 64, b0 = blockIdx.y * 64;
#pragma unroll
    for (int i = 0; i < 8; ++i) {
        unsigned d = h32[(size_t)(k0 + rr) * 128 + b0 / 2 + g * 8 + i];
        const int bl = (g * 8 + i) * 2;
        T[bl][rr]     = (unsigned short)(d & 0xffffu);
        T[bl + 1][rr] = (unsigned short)(d >> 16);
    }
    __syncthreads();
#pragma unroll
    for (int i = 0; i < 8; ++i) {
        const int kl = (g * 8 + i) * 2;
        unsigned d = (unsigned)T[rr][kl] | ((unsigned)T[rr][kl + 1] << 16);
        hT32[(size_t)(b0 + rr) * (NN / 2) + k0 / 2 + g * 8 + i] = d;
    }
}

// ---------------------------------------------------------------------------
// Output GEMM via MFMA, split-K=16, software-pipelined (prefetch dist 1).
// grid (32, 16): o-blocks of 32, k-chunks of 864. Block = 4 waves; wave w
// covers 32o x 64b (2 o-tiles x 4 b-tiles). W_out read once (fp32->bf16 pk-cvt).
// ---------------------------------------------------------------------------
__global__ __launch_bounds__(256) void outgemm_mfma(
    const float* __restrict__ wout, const short* __restrict__ hT,
    float* __restrict__ part)
{
    const int tid = threadIdx.x, w = tid >> 6, lane = tid & 63;
    const int quad = lane >> 4, l16 = lane & 15;
    const int o0 = blockIdx.x * 32;
    const int kb = blockIdx.y * (NN / KS);
    const int b0 = w * 64;

    const int oa = o0 + l16, ob = o0 + 16 + l16;
    const bool av0 = oa < ODIM, av1 = ob < ODIM;
    const float* __restrict__ ar0 = &wout[(size_t)oa * NN];
    const float* __restrict__ ar1 = &wout[(size_t)ob * NN];
    const float4 z4 = {0.f, 0.f, 0.f, 0.f};

    f32x4 acc[2][4] = {};

    int ka = kb + quad * 8;
    float4 a00 = av0 ? *(const float4*)&ar0[ka]     : z4;
    float4 a01 = av0 ? *(const float4*)&ar0[ka + 4] : z4;
    float4 a10 = av1 ? *(const float4*)&ar1[ka]     : z4;
    float4 a11 = av1 ? *(const float4*)&ar1[ka + 4] : z4;
    bf8 bb[4];
#pragma unroll
    for (int j = 0; j < 4; ++j)
        bb[j] = *(const bf8*)&hT[(size_t)(b0 + j * 16 + l16) * NN + ka];

    for (int it = 0; it < 27; ++it) {
        float4 na00{}, na01{}, na10{}, na11{}; bf8 nb[4] = {};
        if (it < 26) {
            const int nka = ka + 32;
            na00 = av0 ? *(const float4*)&ar0[nka]     : z4;
            na01 = av0 ? *(const float4*)&ar0[nka + 4] : z4;
            na10 = av1 ? *(const float4*)&ar1[nka]     : z4;
            na11 = av1 ? *(const float4*)&ar1[nka + 4] : z4;
#pragma unroll
            for (int j = 0; j < 4; ++j)
                nb[j] = *(const bf8*)&hT[(size_t)(b0 + j * 16 + l16) * NN + nka];
        }
        bf8 af0 = cvt8(a00, a01);
        bf8 af1 = cvt8(a10, a11);
#pragma unroll
        for (int j = 0; j < 4; ++j) {
            acc[0][j] = __builtin_amdgcn_mfma_f32_16x16x32_bf16(af0, bb[j], acc[0][j], 0, 0, 0);
            acc[1][j] = __builtin_amdgcn_mfma_f32_16x16x32_bf16(af1, bb[j], acc[1][j], 0, 0, 0);
        }
        a00 = na00; a01 = na01; a10 = na10; a11 = na11;
#pragma unroll
        for (int j = 0; j < 4; ++j) bb[j] = nb[j];
        ka += 32;
    }

#pragma unroll
    for (int i = 0; i < 2; ++i)
#pragma unroll
        for (int j = 0; j < 4; ++j) {
            const int b = b0 + j * 16 + l16;
#pragma unroll
            for (int r = 0; r < 4; ++r) {
                const int o = o0 + i * 16 + quad * 4 + r;
                part[((size_t)blockIdx.y * 1024 + o) * BB + b] = acc[i][j][r];
            }
        }
}

// out[b*1000+o] = bias[o] + sum_kc part[kc][o][b]; block per o, lanes = b.
__global__ __launch_bounds__(256) void reduce_kernel(
    const float* __restrict__ part, const float* __restrict__ bias,
    float* __restrict__ out)
{
    const int o = blockIdx.x, b = threadIdx.x;
    float s = bias[o];
#pragma unroll
    for (int kc = 0; kc < KS; ++kc)
        s += part[((size_t)kc * 1024 + o) * BB + b];
    out[(size_t)b * ODIM + o] = s;
}

extern "C" void kernel_launch(void* const* d_in, const int* in_sizes, int n_in,
                              void* d_out, int out_size, void* d_ws, size_t ws_size,
                              hipStream_t stream)
{
    const float* x       = (const float*)d_in[0];
    const float* w_in    = (const float*)d_in[1];
    const float* b_in    = (const float*)d_in[2];
    const float* w_local = (const float*)d_in[3];
    const float* w_out   = (const float*)d_in[4];
    const float* b_out   = (const float*)d_in[5];
    float* out = (float*)d_out;

    char* p = (char*)d_ws;
    unsigned short* xp_bf = (unsigned short*)p;          p += (size_t)NN * BB * 2;
    unsigned short* hA    = (unsigned short*)p;          p += (size_t)NN * BB * 2;
    unsigned short* hB    = (unsigned short*)p;          p += (size_t)NN * BB * 2;
    unsigned short* hT    = (unsigned short*)p;          p += (size_t)NN * BB * 2;
    unsigned short* x_bf  = (unsigned short*)p;          p += (size_t)BB * KDIM * 2;
    float*          part  = (float*)p;                   // KS*1024*BB floats

    xbf_kernel<<<256, 256, 0, stream>>>(x, (unsigned*)x_bf);
    xproj_mfma<<<864, 256, 0, stream>>>(w_in, b_in, (const short*)x_bf, xp_bf, hA);

    const unsigned* hp = (const unsigned*)hA;
    unsigned* hn = (unsigned*)hB;
    for (int s = 0; s < 29; ++s) {          // 29 odd -> final state in hB
        step_kernel<<<2304, 128, 0, stream>>>(hp, (const unsigned*)xp_bf, w_local, hn);
        unsigned* t = (unsigned*)hp; hp = hn; hn = t;
    }

    transpose_kernel<<<dim3(216, 4), 256, 0, stream>>>(hp, (unsigned*)hT);
    outgemm_mfma<<<dim3(32, KS), 256, 0, stream>>>(w_out, (const short*)hT, part);
    reduce_kernel<<<ODIM, 256, 0, stream>>>(part, b_out, out);
}